// Round 3
// baseline (215.166 us; speedup 1.0000x reference)
//
#include <hip/hip_runtime.h>
#include <hip/hip_bf16.h>

// Problem constants (match reference)
#define BB 512
#define CIN 5
#define LL 1024
#define COUT 32
#define AA 13
#define NBP 5
#define NTOT (BB * LL)          // 524288 positions for BN stats
#define EPSV 1e-5f

// ws layout (floats) — total use: 256 floats (1 KB). No large intermediates.
#define WS_MOM   0    // 40: [s1(5), m1(15), s2(5), m2(15)]
#define WS_SCALE 64   // 64: per concat-channel BN scale
#define WS_SHIFT 128  // 64: per concat-channel BN shift
#define WS_F     192  // 10: F[nn] = sum over half-l of flw

// ---------------- Kernel 1: accumulate depthwise-output moments ----------------
__global__ __launch_bounds__(256) void k_moments(
    const float* __restrict__ src,
    const float* __restrict__ dw1,
    const float* __restrict__ dw2,
    float* __restrict__ ws)
{
    float w1[25], w2[15];
#pragma unroll
    for (int k = 0; k < 25; k++) w1[k] = dw1[k];
#pragma unroll
    for (int k = 0; k < 15; k++) w2[k] = dw2[k];

    float acc[40];
#pragma unroll
    for (int k = 0; k < 40; k++) acc[k] = 0.f;

    int gid = blockIdx.x * 256 + threadIdx.x;
    for (int p = gid; p < NTOT; p += 256 * 256) {
        int b = p >> 10, l = p & 1023;
        const float* sb = src + b * (CIN * LL) + l;
        float d1[5], d2[5];
#pragma unroll
        for (int c5 = 0; c5 < 5; c5++) {
            const float* sp = sb + c5 * LL;
            float x0 = (l >= 2)    ? sp[-2] : 0.f;
            float x1 = (l >= 1)    ? sp[-1] : 0.f;
            float x2 = sp[0];
            float x3 = (l <= 1022) ? sp[1]  : 0.f;
            float x4 = (l <= 1021) ? sp[2]  : 0.f;
            d1[c5] = w1[c5*5+0]*x0 + w1[c5*5+1]*x1 + w1[c5*5+2]*x2 + w1[c5*5+3]*x3 + w1[c5*5+4]*x4;
            d2[c5] = w2[c5*3+0]*x1 + w2[c5*3+1]*x2 + w2[c5*3+2]*x3;
        }
#pragma unroll
        for (int j = 0; j < 5; j++) { acc[j] += d1[j]; acc[20+j] += d2[j]; }
#pragma unroll
        for (int j = 0; j < 5; j++)
#pragma unroll
            for (int k = j; k < 5; k++) {
                int idx = j*(11-j)/2 + (k - j);
                acc[5+idx]  += d1[j]*d1[k];
                acc[25+idx] += d2[j]*d2[k];
            }
    }

    // wave butterfly reduce, then cross-wave via LDS, then one atomic per value per block
#pragma unroll
    for (int k = 0; k < 40; k++) {
        float v = acc[k];
#pragma unroll
        for (int off = 32; off; off >>= 1) v += __shfl_xor(v, off, 64);
        acc[k] = v;
    }
    __shared__ float red[4][40];
    int lane = threadIdx.x & 63, wv = threadIdx.x >> 6;
    if (lane == 0) {
#pragma unroll
        for (int k = 0; k < 40; k++) red[wv][k] = acc[k];
    }
    __syncthreads();
    if (threadIdx.x < 40) {
        float v = red[0][threadIdx.x] + red[1][threadIdx.x] + red[2][threadIdx.x] + red[3][threadIdx.x];
        atomicAdd(&ws[WS_MOM + threadIdx.x], v);
    }
}

// ---------------- Kernel 2: BN scale/shift per channel + flw half-row sums ----------------
__global__ __launch_bounds__(64) void k_finalize(
    float* __restrict__ ws,
    const float* __restrict__ pw1,
    const float* __restrict__ pw2,
    const float* __restrict__ g1,
    const float* __restrict__ be1,
    const float* __restrict__ g2,
    const float* __restrict__ be2,
    const float* __restrict__ flw)
{
    int t = threadIdx.x;        // 0..63
    const float invN = 1.0f / (float)NTOT;
    {
        int br = t >> 5, o = t & 31;
        const float* pw = br ? pw2 : pw1;
        const float* s = ws + WS_MOM + (br ? 20 : 0);
        const float* M = ws + WS_MOM + (br ? 25 : 5);
        float pwv[5], md[5];
#pragma unroll
        for (int j = 0; j < 5; j++) { pwv[j] = pw[o*5+j]; md[j] = s[j] * invN; }
        float meanY = 0.f;
#pragma unroll
        for (int j = 0; j < 5; j++) meanY += pwv[j] * md[j];
        float ey2 = 0.f;
#pragma unroll
        for (int j = 0; j < 5; j++)
#pragma unroll
            for (int k = 0; k < 5; k++) {
                int lo = j < k ? j : k, hi = j < k ? k : j;
                int idx = lo*(11-lo)/2 + (hi - lo);
                ey2 += pwv[j] * pwv[k] * (M[idx] * invN);
            }
        float varY = ey2 - meanY * meanY;
        if (varY < 0.f) varY = 0.f;               // cancellation guard
        float gg = br ? g2[o] : g1[o];
        float bb = br ? be2[o] : be1[o];
        float sc = gg * rsqrtf(varY + EPSV);
        ws[WS_SCALE + t] = sc;
        ws[WS_SHIFT + t] = bb - meanY * sc;
    }
    // F[nn]: sums of flw half-rows (nn<5: first 1024 cols of row nn; nn>=5: last 1024 of row nn-5)
    for (int nn = 0; nn < 10; nn++) {
        int n = nn < 5 ? nn : nn - 5;
        int off = nn < 5 ? 0 : LL;
        float part = 0.f;
        for (int l = t; l < LL; l += 64) part += flw[n * (2*LL) + off + l];
#pragma unroll
        for (int o2 = 32; o2; o2 >>= 1) part += __shfl_xor(part, o2, 64);
        if (t == 0) ws[WS_F + nn] = part;
    }
}

// ---------------- Kernel 3 (fused): e(b,c,l) on the fly -> S[c][nn] in LDS -> PQ -> out ----------------
__global__ __launch_bounds__(256) void k_fused(
    const float* __restrict__ src,
    const float* __restrict__ dw1,
    const float* __restrict__ dw2,
    const float* __restrict__ pw1,
    const float* __restrict__ pw2,
    const float* __restrict__ r1w,
    const float* __restrict__ r1b,
    const float* __restrict__ r2w,
    const float* __restrict__ r2b,
    const float* __restrict__ flw,
    const float* __restrict__ ll1w,
    const float* __restrict__ ll1b,
    const float* __restrict__ flb,
    const float* __restrict__ ws,
    float* __restrict__ out)
{
    __shared__ __align__(16) float srcS[5][260];   // halo +-2 : i -> l = l0 + i - 2
    __shared__ __align__(16) float srcC[5][256];   // centered copy for residual 1x1 conv
    __shared__ __align__(16) float d1S[5][256];
    __shared__ __align__(16) float d2S[5][256];
    __shared__ __align__(16) float flwS[10][256];
    __shared__ __align__(16) float dwS[40];
    __shared__ __align__(16) float red[4][640];    // per-wave-group partial S; red[0] becomes final S
    __shared__ float llT[832];                     // ll1w transposed: llT[c*13 + a]
    __shared__ float PQ[130];                      // [half*65 + a*5 + n]
    __shared__ float Fb[10];
    __shared__ float bbS[13];
    __shared__ float flbS[5];

    int tid = threadIdx.x, b = blockIdx.x;
    int c = tid & 63, g = tid >> 6, o = c & 31, br = c >> 5;

    if (tid < 25) dwS[tid] = dw1[tid];
    else if (tid < 40) dwS[tid] = dw2[tid - 25];
    // stage ll1w transposed + small vectors
    for (int idx = tid; idx < 832; idx += 256) {
        int cc = idx / 13, a = idx - cc * 13;
        llT[idx] = ll1w[a * 64 + cc];
    }
    if (tid < 10) Fb[tid] = ws[WS_F + tid];
    if (tid < 13) bbS[tid] = ll1b[tid];
    if (tid < 5)  flbS[tid] = flb[tid];

    const float* pw = br ? pw2 : pw1;
    const float* rw = br ? r2w : r1w;
    float pwv[5], rwv[5];
#pragma unroll
    for (int j = 0; j < 5; j++) { pwv[j] = pw[o*5+j]; rwv[j] = rw[o*5+j]; }
    float rb = br ? r2b[o] : r1b[o];
    float sc = ws[WS_SCALE + c], sh = ws[WS_SHIFT + c];

    float acc[10];
#pragma unroll
    for (int nn = 0; nn < 10; nn++) acc[nn] = 0.f;

    const float* srcB = src + b * (CIN * LL);

    for (int t = 0; t < 4; t++) {
        int l0 = t * 256;
        __syncthreads();
        // stage src tile with halo
        for (int idx = tid; idx < 5 * 260; idx += 256) {
            int c5 = idx / 260, i = idx - c5 * 260;
            int l = l0 + i - 2;
            srcS[c5][i] = ((unsigned)l < (unsigned)LL) ? srcB[(c5 << 10) + l] : 0.f;
        }
        // stage flw tile (10 half-rows: nn<5 => row nn cols [l0,l0+256); nn>=5 => row nn-5 cols [1024+l0,...))
        for (int idx = tid; idx < 2560; idx += 256) {
            int nn = idx >> 8, i = idx & 255;
            int n = nn < 5 ? nn : nn - 5;
            int off = nn < 5 ? 0 : LL;
            flwS[nn][i] = flw[n * (2*LL) + off + l0 + i];
        }
        __syncthreads();
        // depthwise outputs + centered src copy
        for (int idx = tid; idx < 1280; idx += 256) {
            int c5 = idx >> 8, i = idx & 255;
            const float* sp = &srcS[c5][i];
            float v0 = sp[0], v1 = sp[1], v2 = sp[2], v3 = sp[3], v4 = sp[4];
            d1S[c5][i] = dwS[c5*5+0]*v0 + dwS[c5*5+1]*v1 + dwS[c5*5+2]*v2 + dwS[c5*5+3]*v3 + dwS[c5*5+4]*v4;
            d2S[c5][i] = dwS[25+c5*3+0]*v1 + dwS[25+c5*3+1]*v2 + dwS[25+c5*3+2]*v3;
            srcC[c5][i] = v2;
        }
        __syncthreads();
        // compute e(c, l) and accumulate flw dot products; LDS reads are wave-broadcast friendly
        const float* dS = br ? &d2S[0][0] : &d1S[0][0];
#pragma unroll 4
        for (int ib = g; ib < 64; ib += 4) {
            int i0 = ib * 4;
            float d[5][4], sv[5][4];
#pragma unroll
            for (int j = 0; j < 5; j++) {
                float4 t4 = *(const float4*)&dS[j * 256 + i0];
                d[j][0] = t4.x; d[j][1] = t4.y; d[j][2] = t4.z; d[j][3] = t4.w;
                float4 u4 = *(const float4*)&srcC[j][i0];
                sv[j][0] = u4.x; sv[j][1] = u4.y; sv[j][2] = u4.z; sv[j][3] = u4.w;
            }
            float e[4];
#pragma unroll
            for (int q = 0; q < 4; q++) {
                float y = pwv[0]*d[0][q] + pwv[1]*d[1][q] + pwv[2]*d[2][q] + pwv[3]*d[3][q] + pwv[4]*d[4][q];
                float r = rb + rwv[0]*sv[0][q] + rwv[1]*sv[1][q] + rwv[2]*sv[2][q] + rwv[3]*sv[3][q] + rwv[4]*sv[4][q];
                float yb = fmaxf(fmaf(y, sc, sh), 0.f);
                e[q] = yb * r;
            }
#pragma unroll
            for (int nn = 0; nn < 10; nn++) {
                float4 f4 = *(const float4*)&flwS[nn][i0];
                acc[nn] += e[0]*f4.x + e[1]*f4.y + e[2]*f4.z + e[3]*f4.w;
            }
        }
    }
    __syncthreads();
#pragma unroll
    for (int nn = 0; nn < 10; nn++) red[g][c * 10 + nn] = acc[nn];
    __syncthreads();
    // S[c][nn] = sum over the 4 thread-groups -> red[0][c*10+nn]
    for (int idx = tid; idx < 640; idx += 256)
        red[0][idx] = red[0][idx] + red[1][idx] + red[2][idx] + red[3][idx];
    __syncthreads();
    // PQ[half][a][n] = sum_c llT[c*13+a] * S[c][half*5+n] + ll1b[a]*F[half*5+n]
    if (tid < 130) {
        int half = tid >= 65 ? 1 : 0;
        int q = tid - half * 65;
        int a = q / 5, n = q - a * 5;
        int col = half * 5 + n;
        float v = bbS[a] * Fb[col];
#pragma unroll 8
        for (int cc = 0; cc < 64; cc++) v += llT[cc * 13 + a] * red[0][cc * 10 + col];
        PQ[tid] = v;
    }
    __syncthreads();
    // out[b,i,j,n] = P[min,n] + Q[max,n] + flb[n]
    for (int idx = tid; idx < AA * AA * NBP; idx += 256) {
        int i = idx / 65;
        int rr = idx - i * 65;
        int j = rr / 5, n = rr - j * 5;
        int mn = i < j ? i : j, mx = i < j ? j : i;
        out[b * (AA * AA * NBP) + idx] = PQ[mn * 5 + n] + PQ[65 + mx * 5 + n] + flbS[n];
    }
}

extern "C" void kernel_launch(void* const* d_in, const int* in_sizes, int n_in,
                              void* d_out, int out_size, void* d_ws, size_t ws_size,
                              hipStream_t stream) {
    const float* src  = (const float*)d_in[0];
    // d_in[1] = mask (unused by reference), d_in[2] = max_atoms (unused, == 13)
    const float* dw1  = (const float*)d_in[3];
    const float* pw1  = (const float*)d_in[4];
    const float* g1   = (const float*)d_in[5];
    const float* be1  = (const float*)d_in[6];
    const float* r1w  = (const float*)d_in[7];
    const float* r1b  = (const float*)d_in[8];
    const float* dw2  = (const float*)d_in[9];
    const float* pw2  = (const float*)d_in[10];
    const float* g2   = (const float*)d_in[11];
    const float* be2  = (const float*)d_in[12];
    const float* r2w  = (const float*)d_in[13];
    const float* r2b  = (const float*)d_in[14];
    const float* ll1w = (const float*)d_in[15];
    const float* ll1b = (const float*)d_in[16];
    const float* flw  = (const float*)d_in[17];
    const float* flb  = (const float*)d_in[18];
    float* ws = (float*)d_ws;
    float* out = (float*)d_out;

    // zero the 40 moment accumulators (ws is re-poisoned 0xAA before every launch)
    size_t zbytes = ws_size < 1024 ? ws_size : 1024;
    hipMemsetAsync(d_ws, 0, zbytes, stream);
    k_moments<<<256, 256, 0, stream>>>(src, dw1, dw2, ws);
    k_finalize<<<1, 64, 0, stream>>>(ws, pw1, pw2, g1, be1, g2, be2, flw);
    k_fused<<<BB, 256, 0, stream>>>(src, dw1, dw2, pw1, pw2, r1w, r1b, r2w, r2b,
                                    flw, ll1w, ll1b, flb, ws, out);
}

// Round 4
// 155.344 us; speedup vs baseline: 1.3851x; 1.3851x over previous
//
#include <hip/hip_runtime.h>
#include <hip/hip_bf16.h>

// Problem constants
#define BB 512
#define LL 1024
#define AA 13
#define NBP 5
#define NTOT (BB * LL)
#define EPSV 1e-5f

// ws layout (floats): moments 0..39, F 192..201, packed consts 256..1279
#define WS_MOM   0
#define WS_F     192
#define WS_CONST 256   // 64 channels * 16 floats: [a0..a3][a4,sh,rb,0][r0..r3][r4,0,0,0]

// ---- DPP wave64 sum: result valid in lane 63 (VALU pipe, no LDS) ----
template<int CTRL, int RM, bool BC>
__device__ __forceinline__ float dppadd(float v) {
    int t = __builtin_amdgcn_update_dpp(0, __float_as_int(v), CTRL, RM, 0xf, BC);
    return v + __int_as_float(t);
}
__device__ __forceinline__ float wave_sum(float v) {
    v = dppadd<0x111, 0xf, true >(v);   // row_shr:1
    v = dppadd<0x112, 0xf, true >(v);   // row_shr:2
    v = dppadd<0x114, 0xf, true >(v);   // row_shr:4
    v = dppadd<0x118, 0xf, true >(v);   // row_shr:8  -> lane15 of each row has row sum
    v = dppadd<0x142, 0xa, false>(v);   // row_bcast15 into rows 1,3
    v = dppadd<0x143, 0xc, false>(v);   // row_bcast31 into rows 2,3 -> lane63 total
    return v;
}

// ---------------- Kernel 1: depthwise-output moments + flw half-row sums ----------------
__global__ __launch_bounds__(256) void k_moments(
    const float* __restrict__ src,
    const float* __restrict__ dw1,
    const float* __restrict__ dw2,
    const float* __restrict__ flw,
    float* __restrict__ ws)
{
    __shared__ float red[4][40];
    __shared__ float fred[4];
    int tid = threadIdx.x;
    int gid = blockIdx.x * 256 + tid;
    int b = gid >> 7, L0 = (gid & 127) << 3;     // 8-wide strip
    const float* sb = src + b * (5 * LL);

    float w1[5][5], w2[5][3];
#pragma unroll
    for (int c = 0; c < 5; c++) {
#pragma unroll
        for (int t = 0; t < 5; t++) w1[c][t] = dw1[c*5+t];
#pragma unroll
        for (int t = 0; t < 3; t++) w2[c][t] = dw2[c*3+t];
    }

    // x[c5][i] covers l = L0-4 .. L0+11
    float x[5][16];
#pragma unroll
    for (int c5 = 0; c5 < 5; c5++) {
        const float* sp = sb + c5 * LL;
        float4 xa = (L0 >= 4)     ? *(const float4*)(sp + L0 - 4) : make_float4(0,0,0,0);
        float4 xb = *(const float4*)(sp + L0);
        float4 xc = *(const float4*)(sp + L0 + 4);
        float4 xd = (L0 <= 1012)  ? *(const float4*)(sp + L0 + 8) : make_float4(0,0,0,0);
        x[c5][0]=xa.x; x[c5][1]=xa.y; x[c5][2]=xa.z; x[c5][3]=xa.w;
        x[c5][4]=xb.x; x[c5][5]=xb.y; x[c5][6]=xb.z; x[c5][7]=xb.w;
        x[c5][8]=xc.x; x[c5][9]=xc.y; x[c5][10]=xc.z; x[c5][11]=xc.w;
        x[c5][12]=xd.x; x[c5][13]=xd.y; x[c5][14]=xd.z; x[c5][15]=xd.w;
    }

    float acc[40];
#pragma unroll
    for (int k = 0; k < 40; k++) acc[k] = 0.f;

#pragma unroll
    for (int k = 0; k < 8; k++) {              // l = L0 + k
        float d1[5], d2[5];
#pragma unroll
        for (int c5 = 0; c5 < 5; c5++) {
            // d1 taps l-2..l+2 -> x idx k+2+t ; d2 taps l-1..l+1 -> x idx k+3+t
            d1[c5] = w1[c5][0]*x[c5][k+2] + w1[c5][1]*x[c5][k+3] + w1[c5][2]*x[c5][k+4]
                   + w1[c5][3]*x[c5][k+5] + w1[c5][4]*x[c5][k+6];
            d2[c5] = w2[c5][0]*x[c5][k+3] + w2[c5][1]*x[c5][k+4] + w2[c5][2]*x[c5][k+5];
        }
#pragma unroll
        for (int j = 0; j < 5; j++) { acc[j] += d1[j]; acc[20+j] += d2[j]; }
#pragma unroll
        for (int j = 0; j < 5; j++)
#pragma unroll
            for (int kk = j; kk < 5; kk++) {
                int idx = j*(11-j)/2 + (kk - j);
                acc[5+idx]  += d1[j]*d1[kk];
                acc[25+idx] += d2[j]*d2[kk];
            }
    }

    int lane = tid & 63, wv = tid >> 6;
#pragma unroll
    for (int k = 0; k < 40; k++) acc[k] = wave_sum(acc[k]);
    if (lane == 63) {
#pragma unroll
        for (int k = 0; k < 40; k++) red[wv][k] = acc[k];
    }
    __syncthreads();
    if (tid < 40) {
        float v = red[0][tid] + red[1][tid] + red[2][tid] + red[3][tid];
        atomicAdd(&ws[WS_MOM + tid], v);
    }

    // F[nn] = sum of one flw half-row; blocks 0..9 own one row each (coalesced f4 loads)
    if (blockIdx.x < 10) {
        int nn = blockIdx.x;
        int n = nn < 5 ? nn : nn - 5;
        int off = nn < 5 ? 0 : LL;
        float4 v = *(const float4*)(flw + n * (2*LL) + off + tid * 4);
        float s = wave_sum(v.x + v.y + v.z + v.w);
        if (lane == 63) fred[wv] = s;
        __syncthreads();
        if (tid == 0) ws[WS_F + nn] = fred[0] + fred[1] + fred[2] + fred[3];
    }
}

// ---------------- Kernel 2: BN finalize -> packed per-channel consts (no loops) ----------------
__global__ __launch_bounds__(64) void k_prep(
    float* __restrict__ ws,
    const float* __restrict__ pw1, const float* __restrict__ pw2,
    const float* __restrict__ g1,  const float* __restrict__ be1,
    const float* __restrict__ g2,  const float* __restrict__ be2,
    const float* __restrict__ r1w, const float* __restrict__ r2w,
    const float* __restrict__ r1b, const float* __restrict__ r2b)
{
    int t = threadIdx.x;                 // channel 0..63 (0-31 branch1, 32-63 branch2)
    int br = t >> 5, o = t & 31;
    const float invN = 1.0f / (float)NTOT;
    const float* pw = br ? pw2 : pw1;
    const float* rw = br ? r2w : r1w;
    const float* s  = ws + WS_MOM + (br ? 20 : 0);
    const float* M  = ws + WS_MOM + (br ? 25 : 5);
    float pwv[5], rwv[5], md[5];
#pragma unroll
    for (int j = 0; j < 5; j++) { pwv[j] = pw[o*5+j]; rwv[j] = rw[o*5+j]; md[j] = s[j] * invN; }
    float meanY = 0.f;
#pragma unroll
    for (int j = 0; j < 5; j++) meanY += pwv[j] * md[j];
    float ey2 = 0.f;
#pragma unroll
    for (int j = 0; j < 5; j++)
#pragma unroll
        for (int k = 0; k < 5; k++) {
            int lo = j < k ? j : k, hi = j < k ? k : j;
            int idx = lo*(11-lo)/2 + (hi - lo);
            ey2 += pwv[j] * pwv[k] * (M[idx] * invN);
        }
    float varY = ey2 - meanY * meanY;
    if (varY < 0.f) varY = 0.f;
    float gg = br ? g2[o] : g1[o];
    float bb = br ? be2[o] : be1[o];
    float rb = br ? r2b[o] : r1b[o];
    float sc = gg * rsqrtf(varY + EPSV);
    float sh = bb - meanY * sc;

    float* dst = ws + WS_CONST + t * 16;
    dst[0] = pwv[0]*sc; dst[1] = pwv[1]*sc; dst[2] = pwv[2]*sc; dst[3] = pwv[3]*sc;
    dst[4] = pwv[4]*sc; dst[5] = sh;        dst[6] = rb;        dst[7] = 0.f;
    dst[8] = rwv[0];    dst[9] = rwv[1];    dst[10] = rwv[2];   dst[11] = rwv[3];
    dst[12] = rwv[4];   dst[13] = 0.f;      dst[14] = 0.f;      dst[15] = 0.f;
}

// ---------------- Kernel 3: lanes own l, waves own channel-octets ----------------
__global__ __launch_bounds__(512) void k_fused(
    const float* __restrict__ src,
    const float* __restrict__ dw1,
    const float* __restrict__ dw2,
    const float* __restrict__ flw,
    const float* __restrict__ ll1w,
    const float* __restrict__ ll1b,
    const float* __restrict__ flb,
    const float* __restrict__ ws,
    float* __restrict__ out)
{
    __shared__ __align__(16) float srcS[5][1040];  // i = l + 8, halo zeros at i=6,7 and 1032,1033
    __shared__ __align__(16) float SLds[64][12];   // S[c][nn], padded row for f4 stores
    __shared__ float llT[832];                     // ll1w transposed: [c*13 + a]
    __shared__ float PQ[130];

    int tid = threadIdx.x, b = blockIdx.x;
    int lane = tid & 63;
    int gu = __builtin_amdgcn_readfirstlane(tid >> 6);   // wave id 0..7 (uniform)
    int br = gu >> 2;                                     // waves 0-3 branch1, 4-7 branch2

    const float* srcB = src + b * (5 * LL);

    // stage src (whole L, 5 channels) + halo zeros
    for (int idx = tid; idx < 5 * 256; idx += 512) {
        int c5 = idx >> 8, q = idx & 255;
        float4 v = *(const float4*)(srcB + (c5 << 10) + (q << 2));
        *(float4*)&srcS[c5][(q << 2) + 8] = v;
    }
    if (tid < 5)       { srcS[tid][6] = 0.f; srcS[tid][7] = 0.f; }
    else if (tid < 10) { srcS[tid-5][1032] = 0.f; srcS[tid-5][1033] = 0.f; }
    // stage ll1w transposed
    for (int idx = tid; idx < 832; idx += 512) {
        int cc = idx / 13, a = idx - cc * 13;
        llT[idx] = ll1w[a * 64 + cc];
    }
    __syncthreads();

    // depthwise taps, unified 5-tap window (branch2 padded with zeros) — uniform -> SGPRs
    float wdw[5][5];
    if (br == 0) {
#pragma unroll
        for (int c5 = 0; c5 < 5; c5++)
#pragma unroll
            for (int t = 0; t < 5; t++) wdw[c5][t] = dw1[c5*5+t];
    } else {
#pragma unroll
        for (int c5 = 0; c5 < 5; c5++) {
            wdw[c5][0] = 0.f; wdw[c5][1] = dw2[c5*3+0];
            wdw[c5][2] = dw2[c5*3+1]; wdw[c5][3] = dw2[c5*3+2]; wdw[c5][4] = 0.f;
        }
    }
    const float* cb = ws + WS_CONST + gu * 128;   // 8 channels * 16 floats (uniform base)

    float acc[80];
#pragma unroll
    for (int k = 0; k < 80; k++) acc[k] = 0.f;

#pragma unroll 1
    for (int p = 0; p < 4; p++) {
        int l0 = (p << 8) + (lane << 2);          // this lane's 4 l's
        // flw for these l's: 10 half-rows, lane-varying coalesced f4 global loads
        float4 fw[10];
#pragma unroll
        for (int nn = 0; nn < 10; nn++) {
            int n = nn < 5 ? nn : nn - 5;
            int off = nn < 5 ? 0 : LL;
            fw[nn] = *(const float4*)(flw + n * (2*LL) + off + l0);
        }
        // src window + depthwise (lane-varying LDS reads: full bandwidth)
        float dv[5][4], sv[5][4];
#pragma unroll
        for (int c5 = 0; c5 < 5; c5++) {
            int i0 = l0 + 8;
            float2 lh = *(const float2*)&srcS[c5][i0 - 2];
            float4 ct = *(const float4*)&srcS[c5][i0];
            float2 rh = *(const float2*)&srcS[c5][i0 + 4];
            float xx[8] = {lh.x, lh.y, ct.x, ct.y, ct.z, ct.w, rh.x, rh.y}; // l0-2..l0+5
            sv[c5][0] = ct.x; sv[c5][1] = ct.y; sv[c5][2] = ct.z; sv[c5][3] = ct.w;
#pragma unroll
            for (int q = 0; q < 4; q++)
                dv[c5][q] = wdw[c5][0]*xx[q]   + wdw[c5][1]*xx[q+1] + wdw[c5][2]*xx[q+2]
                          + wdw[c5][3]*xx[q+3] + wdw[c5][4]*xx[q+4];
        }
        // 8 channels of this wave: consts via scalar loads (uniform address)
#pragma unroll
        for (int ci = 0; ci < 8; ci++) {
            const float4 A  = *(const float4*)(cb + ci*16);      // a0..a3 (pw*sc)
            const float4 B2 = *(const float4*)(cb + ci*16 + 4);  // a4, sh, rb
            const float4 R0 = *(const float4*)(cb + ci*16 + 8);  // r0..r3
            const float4 R1 = *(const float4*)(cb + ci*16 + 12); // r4
#pragma unroll
            for (int q = 0; q < 4; q++) {
                float y = B2.y + A.x*dv[0][q] + A.y*dv[1][q] + A.z*dv[2][q]
                                + A.w*dv[3][q] + B2.x*dv[4][q];
                float r = B2.z + R0.x*sv[0][q] + R0.y*sv[1][q] + R0.z*sv[2][q]
                                + R0.w*sv[3][q] + R1.x*sv[4][q];
                float e = fmaxf(y, 0.f) * r;
#pragma unroll
                for (int nn = 0; nn < 10; nn++) {
                    float f = (nn==0)?fw[0].x:(nn==1)?fw[1].x:(nn==2)?fw[2].x:(nn==3)?fw[3].x:
                              (nn==4)?fw[4].x:(nn==5)?fw[5].x:(nn==6)?fw[6].x:(nn==7)?fw[7].x:
                              (nn==8)?fw[8].x:fw[9].x;
                    float fq = (q==0) ? f :
                               (q==1) ? ((nn==0)?fw[0].y:(nn==1)?fw[1].y:(nn==2)?fw[2].y:(nn==3)?fw[3].y:
                                         (nn==4)?fw[4].y:(nn==5)?fw[5].y:(nn==6)?fw[6].y:(nn==7)?fw[7].y:
                                         (nn==8)?fw[8].y:fw[9].y) :
                               (q==2) ? ((nn==0)?fw[0].z:(nn==1)?fw[1].z:(nn==2)?fw[2].z:(nn==3)?fw[3].z:
                                         (nn==4)?fw[4].z:(nn==5)?fw[5].z:(nn==6)?fw[6].z:(nn==7)?fw[7].z:
                                         (nn==8)?fw[8].z:fw[9].z) :
                                        ((nn==0)?fw[0].w:(nn==1)?fw[1].w:(nn==2)?fw[2].w:(nn==3)?fw[3].w:
                                         (nn==4)?fw[4].w:(nn==5)?fw[5].w:(nn==6)?fw[6].w:(nn==7)?fw[7].w:
                                         (nn==8)?fw[8].w:fw[9].w);
                    acc[ci*10 + nn] += e * fq;
                }
            }
        }
    }

    // reduce each acc over the 64 lanes (DPP, VALU pipe); lane 63 writes S row
#pragma unroll
    for (int k = 0; k < 80; k++) acc[k] = wave_sum(acc[k]);
    if (lane == 63) {
#pragma unroll
        for (int ci = 0; ci < 8; ci++) {
            int c = gu * 8 + ci;
            *(float4*)&SLds[c][0] = make_float4(acc[ci*10+0], acc[ci*10+1], acc[ci*10+2], acc[ci*10+3]);
            *(float4*)&SLds[c][4] = make_float4(acc[ci*10+4], acc[ci*10+5], acc[ci*10+6], acc[ci*10+7]);
            *(float2*)&SLds[c][8] = make_float2(acc[ci*10+8], acc[ci*10+9]);
        }
    }
    __syncthreads();

    // PQ[half][a][n] = sum_c llT[c][a] * S[c][half*5+n] + ll1b[a] * F[half*5+n]
    if (tid < 130) {
        int half = tid >= 65 ? 1 : 0;
        int q = tid - half * 65;
        int a = q / 5, n = q - a * 5;
        int col = half * 5 + n;
        float v = ll1b[a] * ws[WS_F + col];
#pragma unroll 8
        for (int cc = 0; cc < 64; cc++) v += llT[cc * 13 + a] * SLds[cc][col];
        PQ[tid] = v;
    }
    __syncthreads();

    // out[b,i,j,n] = P[min,n] + Q[max,n] + flb[n]
    for (int idx = tid; idx < AA * AA * NBP; idx += 512) {
        int i = idx / 65;
        int rr = idx - i * 65;
        int j = rr / 5, n = rr - j * 5;
        int mn = i < j ? i : j, mx = i < j ? j : i;
        out[b * (AA * AA * NBP) + idx] = PQ[mn * 5 + n] + PQ[65 + mx * 5 + n] + flb[n];
    }
}

extern "C" void kernel_launch(void* const* d_in, const int* in_sizes, int n_in,
                              void* d_out, int out_size, void* d_ws, size_t ws_size,
                              hipStream_t stream) {
    const float* src  = (const float*)d_in[0];
    // d_in[1] = mask (unused), d_in[2] = max_atoms (unused, == 13)
    const float* dw1  = (const float*)d_in[3];
    const float* pw1  = (const float*)d_in[4];
    const float* g1   = (const float*)d_in[5];
    const float* be1  = (const float*)d_in[6];
    const float* r1w  = (const float*)d_in[7];
    const float* r1b  = (const float*)d_in[8];
    const float* dw2  = (const float*)d_in[9];
    const float* pw2  = (const float*)d_in[10];
    const float* g2   = (const float*)d_in[11];
    const float* be2  = (const float*)d_in[12];
    const float* r2w  = (const float*)d_in[13];
    const float* r2b  = (const float*)d_in[14];
    const float* ll1w = (const float*)d_in[15];
    const float* ll1b = (const float*)d_in[16];
    const float* flw  = (const float*)d_in[17];
    const float* flb  = (const float*)d_in[18];
    float* ws  = (float*)d_ws;
    float* out = (float*)d_out;

    hipMemsetAsync(d_ws, 0, 1024, stream);   // zero moments + F accumulators
    k_moments<<<256, 256, 0, stream>>>(src, dw1, dw2, flw, ws);
    k_prep<<<1, 64, 0, stream>>>(ws, pw1, pw2, g1, be1, g2, be2, r1w, r2w, r1b, r2b);
    k_fused<<<BB, 512, 0, stream>>>(src, dw1, dw2, flw, ll1w, ll1b, flb, ws, out);
}